// Round 19
// baseline (21.958 us; speedup 1.0000x reference)
//
#include <hip/hip_runtime.h>
#include <math.h>

#define BATCH   512
#define IN_DIM  256
#define OUT_DIM 256

// R19: best-known config (R15: NB=16, grid 32x32, 4 blocks/CU) in PURE C
// (R18-proven safe, no inline-asm risk class), plus the one untried overlap:
// the g=0 coefficient build (24 scattered global loads + 48 exps, NO LDS
// dependency) is HOISTED ABOVE the t-staging block, so its load latency
// hides under staging's exp+LDS-write phase instead of serializing after
// the barrier. Only one coef bank live at a time (R11's two-bank prefetch
// failure mode avoided): acc16 + 48 coefs + transients ~= 95 VGPR < 128.
#define OT     8     // o per block
#define NSEG   32    // i-segments per block (tid>>3)
#define ISEG   8     // i's per segment
#define NB     16    // b per block (register accumulators)

#define PRESCALE 12.476649250079015f   // 18 * ln2

// Grid = (OUT_DIM/OT = 32, BATCH/NB = 32) = 1024 blocks. One dispatch.
__launch_bounds__(256, 4)
__global__ void tropical_fused(const float* __restrict__ x,
                               const float* __restrict__ wp,
                               const float* __restrict__ wq,
                               float* __restrict__ out) {
    // Phase A: t[b][i], 16 b x 256 i (4096 f). Phase B: slab reduce
    // (32 slabs, stride NB*OT+1 = 129 -> 4128 f). Shared allocation.
    __shared__ float lds[NSEG * (NB * OT + 1)];   // 4128 floats = 16.5 KiB

    const int tid = threadIdx.x;
    const int o_l = tid & (OT - 1);
    const int b0  = blockIdx.y * NB;

    const int seg    = tid >> 3;           // 0..31
    const int i_base = seg * ISEG;
    const int o      = blockIdx.x * OT + o_l;

    // ---- g=0 coefficient build FIRST (no LDS dep; loads overlap staging) ----
    float cp[4][6], cq[4][6];
#pragma unroll
    for (int ii = 0; ii < 4; ++ii) {
        const int j = (i_base + ii) * OUT_DIM + o;
        const float2* P2 = (const float2*)wp + (size_t)j * 3;
        const float2* Q2 = (const float2*)wq + (size_t)j * 3;
        const float2 p0 = P2[0], p1 = P2[1], p2 = P2[2];
        const float2 q0 = Q2[0], q1 = Q2[1], q2 = Q2[2];
        cp[ii][0] = __expf(p0.x - PRESCALE);
        cp[ii][1] = __expf(p0.y - PRESCALE);
        cp[ii][2] = __expf(p1.x - PRESCALE);
        cp[ii][3] = __expf(p1.y - PRESCALE);
        cp[ii][4] = __expf(p2.x - PRESCALE);
        cp[ii][5] = __expf(p2.y - PRESCALE);
        cq[ii][0] = __expf(q0.x - PRESCALE);
        cq[ii][1] = __expf(q0.y - PRESCALE);
        cq[ii][2] = __expf(q1.x - PRESCALE);
        cq[ii][3] = __expf(q1.y - PRESCALE);
        cq[ii][4] = __expf(q2.x - PRESCALE);
        cq[ii][5] = __expf(q2.y - PRESCALE);
    }

    // ---- stage t = exp(x): 16 b-rows x 256 i (16 floats / thread) ----
    {
        const int r = tid >> 4;            // 0..15
        const int c = (tid & 15) * 16;     // 0..240
        const float* xr = x + (size_t)(b0 + r) * IN_DIM + c;
#pragma unroll
        for (int q = 0; q < 4; ++q) {
            const float4 v = *(const float4*)(xr + q * 4);
            float4 w;
            w.x = __expf(v.x); w.y = __expf(v.y);
            w.z = __expf(v.z); w.w = __expf(v.w);
            *(float4*)&lds[r * IN_DIM + c + q * 4] = w;
        }
    }
    __syncthreads();

    float acc[NB];
#pragma unroll
    for (int b = 0; b < NB; ++b) acc[b] = 0.f;

    const float* __restrict__ tb = lds + i_base;

#pragma unroll
    for (int g = 0; g < 2; ++g) {          // 2 groups of 4 i's
        if (g == 1) {
            // ---- g=1 coefficient build (after g=0 inner loop) ----
#pragma unroll
            for (int ii = 0; ii < 4; ++ii) {
                const int j = (i_base + 4 + ii) * OUT_DIM + o;
                const float2* P2 = (const float2*)wp + (size_t)j * 3;
                const float2* Q2 = (const float2*)wq + (size_t)j * 3;
                const float2 p0 = P2[0], p1 = P2[1], p2 = P2[2];
                const float2 q0 = Q2[0], q1 = Q2[1], q2 = Q2[2];
                cp[ii][0] = __expf(p0.x - PRESCALE);
                cp[ii][1] = __expf(p0.y - PRESCALE);
                cp[ii][2] = __expf(p1.x - PRESCALE);
                cp[ii][3] = __expf(p1.y - PRESCALE);
                cp[ii][4] = __expf(p2.x - PRESCALE);
                cp[ii][5] = __expf(p2.y - PRESCALE);
                cq[ii][0] = __expf(q0.x - PRESCALE);
                cq[ii][1] = __expf(q0.y - PRESCALE);
                cq[ii][2] = __expf(q1.x - PRESCALE);
                cq[ii][3] = __expf(q1.y - PRESCALE);
                cq[ii][4] = __expf(q2.x - PRESCALE);
                cq[ii][5] = __expf(q2.y - PRESCALE);
            }
        }

        // ---- inner loop: scalar Horner x (P,Q) x 4 i's, 1 log2 pair ----
#pragma unroll
        for (int b = 0; b < NB; ++b) {
            const float4 tv = *(const float4*)(tb + b * IN_DIM + g * 4);
            const float t0 = tv.x, t1 = tv.y, t2 = tv.z, t3 = tv.w;

            const float P0 = fmaf(fmaf(fmaf(fmaf(fmaf(cp[0][5], t0, cp[0][4]),
                t0, cp[0][3]), t0, cp[0][2]), t0, cp[0][1]), t0, cp[0][0]);
            const float P1 = fmaf(fmaf(fmaf(fmaf(fmaf(cp[1][5], t1, cp[1][4]),
                t1, cp[1][3]), t1, cp[1][2]), t1, cp[1][1]), t1, cp[1][0]);
            const float P2v = fmaf(fmaf(fmaf(fmaf(fmaf(cp[2][5], t2, cp[2][4]),
                t2, cp[2][3]), t2, cp[2][2]), t2, cp[2][1]), t2, cp[2][0]);
            const float P3 = fmaf(fmaf(fmaf(fmaf(fmaf(cp[3][5], t3, cp[3][4]),
                t3, cp[3][3]), t3, cp[3][2]), t3, cp[3][1]), t3, cp[3][0]);

            const float Q0 = fmaf(fmaf(fmaf(fmaf(fmaf(cq[0][5], t0, cq[0][4]),
                t0, cq[0][3]), t0, cq[0][2]), t0, cq[0][1]), t0, cq[0][0]);
            const float Q1 = fmaf(fmaf(fmaf(fmaf(fmaf(cq[1][5], t1, cq[1][4]),
                t1, cq[1][3]), t1, cq[1][2]), t1, cq[1][1]), t1, cq[1][0]);
            const float Q2v = fmaf(fmaf(fmaf(fmaf(fmaf(cq[2][5], t2, cq[2][4]),
                t2, cq[2][3]), t2, cq[2][2]), t2, cq[2][1]), t2, cq[2][0]);
            const float Q3 = fmaf(fmaf(fmaf(fmaf(fmaf(cq[3][5], t3, cq[3][4]),
                t3, cq[3][3]), t3, cq[3][2]), t3, cq[3][1]), t3, cq[3][0]);

            const float mp = (P0 * P1) * (P2v * P3);   // in [7e-23, 1.6e21]
            const float mq = (Q0 * Q1) * (Q2v * Q3);
            acc[b] += __log2f(mp) - __log2f(mq);
        }
    }

    __syncthreads();   // done with t; reuse LDS as reduce buffer
#pragma unroll
    for (int b = 0; b < NB; ++b)
        lds[seg * (NB * OT + 1) + b * OT + o_l] = acc[b];
    __syncthreads();

    if (tid < NB * OT) {                   // 128 outputs
        const int br = tid >> 3, orr = tid & (OT - 1);
        float s = 0.f;
#pragma unroll
        for (int g2 = 0; g2 < NSEG; ++g2)
            s += lds[g2 * (NB * OT + 1) + br * OT + orr];
        out[(size_t)(b0 + br) * OUT_DIM + blockIdx.x * OT + orr] =
            s * 0.6931471805599453f;   // * ln2
    }
}

extern "C" void kernel_launch(void* const* d_in, const int* in_sizes, int n_in,
                              void* d_out, int out_size, void* d_ws, size_t ws_size,
                              hipStream_t stream) {
    const float* x  = (const float*)d_in[0];
    // d_in[1] = slopes (arange(6)) — implicit in the polynomial powers.
    const float* wp = (const float*)d_in[2];
    const float* wq = (const float*)d_in[3];
    float* out = (float*)d_out;

    dim3 grid(OUT_DIM / OT, BATCH / NB);   // 32 x 32 = 1024 blocks
    tropical_fused<<<grid, 256, 0, stream>>>(x, wp, wq, out);
}

// Round 20
// 20.260 us; speedup vs baseline: 1.0838x; 1.0838x over previous
//
#include <hip/hip_runtime.h>
#include <math.h>

#define BATCH   512
#define IN_DIM  256
#define OUT_DIM 256

// FINAL (R15-exact revert): fused single-dispatch, NB=16, packed op_sel
// Horner. Best measured config: 20.08 us. Ladder summary:
//   R3  coef-in-registers (16x reuse)        56 -> 28 us
//   R9/R10 2^-18 prescale 4-i log batch + op_sel broadcast  25.3 -> 23.3
//   R14 single-dispatch fusion                23.1 -> 22.2
//   R15 NB=16 (redundancy halving)            22.2 -> 20.1
// Explored-and-closed: coalesced coef layout (null), NB=32 (par; NaN under
// asm x 32-unroll regalloc -- pure-C proves logic fine), software prefetch
// (null x3), scalar Horner at NB=16 (+1.9us: issue-stream doubling), hoist
// (neg). Residual ~11us over the ~9us pipe floor = instruction-issue
// overhead; next structure down is hand-scheduled asm.
#define OT     8     // o per block
#define NSEG   32    // i-segments per block (tid>>3)
#define ISEG   8     // i's per segment
#define NB     16    // b per block (register accumulators)

typedef float v2f __attribute__((ext_vector_type(2)));

// R12 finding: v_pk_fma_f32 has NO execution-throughput edge on CDNA4
// (2-pass); its win at NB=16 is ISSUE-slot compression (R19 A/B: -1.9us).
__device__ __forceinline__ v2f pk_fma_blo(v2f a, v2f t, v2f c) {
    v2f d;
    asm("v_pk_fma_f32 %0, %1, %2, %3 op_sel:[0,0,0] op_sel_hi:[1,0,1]"
        : "=v"(d) : "v"(a), "v"(t), "v"(c));
    return d;
}
__device__ __forceinline__ v2f pk_fma_bhi(v2f a, v2f t, v2f c) {
    v2f d;
    asm("v_pk_fma_f32 %0, %1, %2, %3 op_sel:[0,1,0] op_sel_hi:[1,1,1]"
        : "=v"(d) : "v"(a), "v"(t), "v"(c));
    return d;
}
__device__ __forceinline__ v2f pk_mul(v2f a, v2f b) {
    v2f d;
    asm("v_pk_mul_f32 %0, %1, %2" : "=v"(d) : "v"(a), "v"(b));
    return d;
}

#define PRESCALE 12.476649250079015f   // 18 * ln2

// Packed Horner, t broadcast via op_sel from a (t0,t1) register pair.
__device__ __forceinline__ v2f horner_lo(float4 c0, float4 c1, float4 c2, v2f tp) {
    const v2f C0 = {c0.x, c0.y}, C1 = {c0.z, c0.w};
    const v2f C2 = {c1.x, c1.y}, C3 = {c1.z, c1.w};
    const v2f C4 = {c2.x, c2.y}, C5 = {c2.z, c2.w};
    v2f r = pk_fma_blo(C5, tp, C4);
    r = pk_fma_blo(r, tp, C3);
    r = pk_fma_blo(r, tp, C2);
    r = pk_fma_blo(r, tp, C1);
    r = pk_fma_blo(r, tp, C0);
    return r;
}
__device__ __forceinline__ v2f horner_hi(float4 c0, float4 c1, float4 c2, v2f tp) {
    const v2f C0 = {c0.x, c0.y}, C1 = {c0.z, c0.w};
    const v2f C2 = {c1.x, c1.y}, C3 = {c1.z, c1.w};
    const v2f C4 = {c2.x, c2.y}, C5 = {c2.z, c2.w};
    v2f r = pk_fma_bhi(C5, tp, C4);
    r = pk_fma_bhi(r, tp, C3);
    r = pk_fma_bhi(r, tp, C2);
    r = pk_fma_bhi(r, tp, C1);
    r = pk_fma_bhi(r, tp, C0);
    return r;
}

// Grid = (OUT_DIM/OT = 32, BATCH/NB = 32) = 1024 blocks = 4/CU. One dispatch.
__launch_bounds__(256, 4)
__global__ void tropical_fused(const float* __restrict__ x,
                               const float* __restrict__ wp,
                               const float* __restrict__ wq,
                               float* __restrict__ out) {
    // Phase A: t[b][i], 16 b x 256 i (4096 f). Phase B: slab reduce
    // (32 slabs, stride NB*OT+1 = 129 -> 4128 f). Shared allocation.
    __shared__ float lds[NSEG * (NB * OT + 1)];   // 4128 floats = 16.5 KiB

    const int tid = threadIdx.x;
    const int o_l = tid & (OT - 1);
    const int b0  = blockIdx.y * NB;

    // ---- stage t = exp(x): 16 b-rows x 256 i (16 floats / thread) ----
    {
        const int r = tid >> 4;            // 0..15
        const int c = (tid & 15) * 16;     // 0..240
        const float* xr = x + (size_t)(b0 + r) * IN_DIM + c;
#pragma unroll
        for (int q = 0; q < 4; ++q) {
            const float4 v = *(const float4*)(xr + q * 4);
            float4 w;
            w.x = __expf(v.x); w.y = __expf(v.y);
            w.z = __expf(v.z); w.w = __expf(v.w);
            *(float4*)&lds[r * IN_DIM + c + q * 4] = w;
        }
    }
    __syncthreads();

    float acc[NB];
#pragma unroll
    for (int b = 0; b < NB; ++b) acc[b] = 0.f;

    const int seg    = tid >> 3;           // 0..31
    const int i_base = seg * ISEG;
    const int o      = blockIdx.x * OT + o_l;
    const float* __restrict__ tb = lds + i_base;

#pragma unroll
    for (int g = 0; g < 2; ++g) {          // 2 groups of 4 i's
        // ---- in-register coefficient build: exp(w - 18ln2) ----
        float4 C[12];
#pragma unroll
        for (int ii = 0; ii < 4; ++ii) {
            const int j = (i_base + g * 4 + ii) * OUT_DIM + o;
            const float2* P2 = (const float2*)wp + (size_t)j * 3;
            const float2* Q2 = (const float2*)wq + (size_t)j * 3;
            const float2 p0 = P2[0], p1 = P2[1], p2 = P2[2];
            const float2 q0 = Q2[0], q1 = Q2[1], q2 = Q2[2];
            C[ii * 3 + 0] = make_float4(
                __expf(p0.x - PRESCALE), __expf(q0.x - PRESCALE),
                __expf(p0.y - PRESCALE), __expf(q0.y - PRESCALE));
            C[ii * 3 + 1] = make_float4(
                __expf(p1.x - PRESCALE), __expf(q1.x - PRESCALE),
                __expf(p1.y - PRESCALE), __expf(q1.y - PRESCALE));
            C[ii * 3 + 2] = make_float4(
                __expf(p2.x - PRESCALE), __expf(q2.x - PRESCALE),
                __expf(p2.y - PRESCALE), __expf(q2.y - PRESCALE));
        }

        // ---- VALU-bound inner loop (R10 body, NB=16) ----
#pragma unroll
        for (int b = 0; b < NB; ++b) {
            const float4 tv = *(const float4*)(tb + b * IN_DIM + g * 4);
            const v2f txy = {tv.x, tv.y};
            const v2f tzw = {tv.z, tv.w};
            const v2f PQ0 = horner_lo(C[0], C[1],  C[2],  txy);
            const v2f PQ1 = horner_hi(C[3], C[4],  C[5],  txy);
            const v2f PQ2 = horner_lo(C[6], C[7],  C[8],  tzw);
            const v2f PQ3 = horner_hi(C[9], C[10], C[11], tzw);
            const v2f m = pk_mul(pk_mul(PQ0, PQ1), pk_mul(PQ2, PQ3));
            acc[b] += __log2f(m.x) - __log2f(m.y);
        }
    }

    __syncthreads();   // done with t; reuse LDS as reduce buffer
#pragma unroll
    for (int b = 0; b < NB; ++b)
        lds[seg * (NB * OT + 1) + b * OT + o_l] = acc[b];
    __syncthreads();

    if (tid < NB * OT) {                   // 128 outputs
        const int br = tid >> 3, orr = tid & (OT - 1);
        float s = 0.f;
#pragma unroll
        for (int g2 = 0; g2 < NSEG; ++g2)
            s += lds[g2 * (NB * OT + 1) + br * OT + orr];
        out[(size_t)(b0 + br) * OUT_DIM + blockIdx.x * OT + orr] =
            s * 0.6931471805599453f;   // * ln2
    }
}

extern "C" void kernel_launch(void* const* d_in, const int* in_sizes, int n_in,
                              void* d_out, int out_size, void* d_ws, size_t ws_size,
                              hipStream_t stream) {
    const float* x  = (const float*)d_in[0];
    // d_in[1] = slopes (arange(6)) — implicit in the polynomial powers.
    const float* wp = (const float*)d_in[2];
    const float* wq = (const float*)d_in[3];
    float* out = (float*)d_out;

    dim3 grid(OUT_DIM / OT, BATCH / NB);   // 32 x 32 = 1024 blocks
    tropical_fused<<<grid, 256, 0, stream>>>(x, wp, wq, out);
}